// Round 12
// baseline (237.576 us; speedup 1.0000x reference)
//
#include <hip/hip_runtime.h>
#include <hip/hip_bf16.h>

#define B_   2
#define N_   16384
#define H_   8
#define GS_  256
#define NG_  64

typedef unsigned short u16;
typedef __attribute__((ext_vector_type(8))) short bf16x8;
typedef __attribute__((ext_vector_type(4))) float f32x4;
typedef __attribute__((ext_vector_type(8))) unsigned short us8;
typedef __attribute__((ext_vector_type(4))) unsigned short us4;
typedef __attribute__((ext_vector_type(4))) unsigned int u32x4;
typedef __attribute__((ext_vector_type(2))) unsigned int u32x2;

__device__ __forceinline__ u16 f2b(float f){
  union { float f; unsigned u; } v; v.f = f;
  unsigned r = v.u + 0x7fffu + ((v.u >> 16) & 1u);
  return (u16)(r >> 16);
}

__device__ __forceinline__ u16 f2bh(float f){
  __hip_bfloat16 h = __float2bfloat16(f);
  u16 u; __builtin_memcpy(&u, &h, 2);
  return u;
}

// pack two floats into one u32 of 2 bf16 (lo = a, hi = b)
__device__ __forceinline__ unsigned pk2(float a, float b){
  return ((unsigned)f2b(b) << 16) | (unsigned)f2b(a);
}

__device__ __forceinline__ void gload16(const void* g, const void* lds){
  __builtin_amdgcn_global_load_lds(
      (const __attribute__((address_space(1))) void*)g,
      (__attribute__((address_space(3))) void*)lds, 16, 0, 0);
}

// swizzled 16B fragment read from a [rows][64] bf16 tile (row stride 128B)
__device__ __forceinline__ bf16x8 lds_read8(const u16* base, int row, int coloff){
  int byte = (row*128 + coloff) ^ ((row & 7) << 4);
  return *(const bf16x8*)((const char*)base + byte);
}

__device__ __forceinline__ void stout(float* p, float v){ *p = v; }
__device__ __forceinline__ void stout(u16* p, float v){ *p = f2b(v); }

// ---------------- fp32 -> bf16 vector convert ----------------
__global__ void cvt_f32_bf16(const float4* __restrict__ in, us4* __restrict__ out, int n4){
  int i = blockIdx.x * 256 + threadIdx.x;
  if (i < n4){
    float4 v = in[i];
    us4 o;
    o[0] = f2b(v.x); o[1] = f2b(v.y); o[2] = f2b(v.z); o[3] = f2b(v.w);
    out[i] = o;
  }
}

// ---------------- weight convert + transpose: T[n][k] = bf16(W[k][n]) ----------------
__global__ void cvt_w_t(const float* __restrict__ W0, const float* __restrict__ W1,
                        const float* __restrict__ W2, const float* __restrict__ W3,
                        u16* __restrict__ T0, u16* __restrict__ T1,
                        u16* __restrict__ T2, u16* __restrict__ T3)
{
  int z = blockIdx.z;
  const float* W = (z==0)?W0:((z==1)?W1:((z==2)?W2:W3));
  u16* T = (z==0)?T0:((z==1)?T1:((z==2)?T2:T3));
  __shared__ float tile[16][17];
  int tx = threadIdx.x & 15, ty = threadIdx.x >> 4;
  int k0 = blockIdx.x*16, n0 = blockIdx.y*16;
  tile[ty][tx] = W[(k0+ty)*512 + n0 + tx];
  __syncthreads();
  T[(n0+ty)*512 + k0 + tx] = f2b(tile[tx][ty]);
}

// ---------------- bf16 GEMM: C = A @ Wt^T (R8-proven form) ----------------
template<typename OUT_T, bool MULTI, bool GATHA, bool SCATC>
__global__ __launch_bounds__(256, 2) void gemm_bf16k(
    const u16* __restrict__ A,
    const u16* __restrict__ Wt0, const u16* __restrict__ Wt1, const u16* __restrict__ Wt2,
    const int* __restrict__ perm,   // [B][N] permutation
    OUT_T* __restrict__ C, int ldc)
{
  __shared__ u16 Al[128*64];
  __shared__ u16 Bl[128*64];
  const int tid = threadIdx.x;
  const int l = tid & 63, w = tid >> 6;
  const int lr = l & 15, lg = l >> 4;
  const int bm = blockIdx.x, bn = blockIdx.y;
  const int wr = (w >> 1) * 64, wc = (w & 1) * 64;

  const u16* Wt; int ocolb; float qsc;
  if (MULTI){
    int wsel = bn >> 2;
    Wt = (wsel == 0) ? Wt0 : ((wsel == 1) ? Wt1 : Wt2);
    ocolb = (bn & 3) * 128;
    qsc = (wsel == 0) ? 0.18033688f : 1.0f;   // 0.125 * log2(e)
  } else { Wt = Wt0; ocolb = bn * 128; qsc = 1.0f; }

  int arows[4];
#pragma unroll
  for (int i = 0; i < 4; ++i){
    int r = bm*128 + i*32 + (tid >> 3);
    arows[i] = GATHA ? ((r & ~(N_-1)) + perm[r]) : r;
  }

  f32x4 acc[4][4];
#pragma unroll
  for (int m = 0; m < 4; ++m)
#pragma unroll
    for (int n = 0; n < 4; ++n) acc[m][n] = (f32x4){0.f,0.f,0.f,0.f};

  const int c8 = tid & 7;
  for (int kk = 0; kk < 512; kk += 64){
#pragma unroll
    for (int i = 0; i < 4; ++i){
      int o = i*4096 + tid*16;
      int brow = o >> 7;
      gload16(A  + (size_t)arows[i]*512 + kk + c8*8, (const char*)Al + i*4096 + w*1024);
      gload16(Wt + (size_t)(ocolb + brow)*512 + kk + c8*8, (const char*)Bl + i*4096 + w*1024);
    }
    __syncthreads();
#pragma unroll
    for (int ks = 0; ks < 2; ++ks){
      bf16x8 af[4], bfv[4];
#pragma unroll
      for (int m = 0; m < 4; ++m) af[m]  = *(const bf16x8*)&Al[(wr + m*16 + lr)*64 + ks*32 + lg*8];
#pragma unroll
      for (int n = 0; n < 4; ++n) bfv[n] = *(const bf16x8*)&Bl[(wc + n*16 + lr)*64 + ks*32 + lg*8];
#pragma unroll
      for (int m = 0; m < 4; ++m)
#pragma unroll
        for (int n = 0; n < 4; ++n)
          acc[m][n] = __builtin_amdgcn_mfma_f32_16x16x32_bf16(af[m], bfv[n], acc[m][n], 0, 0, 0);
    }
    __syncthreads();
  }
#pragma unroll
  for (int m = 0; m < 4; ++m)
#pragma unroll
    for (int n = 0; n < 4; ++n)
#pragma unroll
      for (int j = 0; j < 4; ++j){
        int row = bm*128 + wr + m*16 + lg*4 + j;
        int col = bn*128 + wc + n*16 + lr;
        size_t orow = SCATC ? (size_t)((row & ~(N_-1)) + perm[row]) : (size_t)row;
        stout(&C[orow*ldc + col], acc[m][n][j] * qsc);
      }
}

// ---- K tile via global_load_lds, PRE-SWIZZLED SOURCE (m173): LDS stays linear,
// source chunk index xor'd so lds_read8's XOR retrieves the right data.
// Legal: K rows are sequential tokens; within-row permutation keeps coalescing.
#define ISSUEK(c, kbuf) do { int c_ = (c); \
  _Pragma("unroll") for (int i_ = 0; i_ < 2; ++i_){ \
    int row_ = i_*32 + (tid >> 3); \
    int cc_ = ((tid & 7) ^ (row_ & 7)) * 8; \
    const u16* src_; \
    if (c_ < 8){ \
      int p_ = g*GS_ + c_*64 + row_; \
      int gi_ = (p_ < N_) ? p_ : (2*N_ - 1 - p_); \
      src_ = qkv + (size_t)(b*N_ + gi_)*1536 + 512 + h*64 + cc_; \
    } else { \
      src_ = kgb + (size_t)(h*64 + row_)*64 + cc_; \
    } \
    gload16(src_, (const char*)(kbuf) + i_*4096 + w*1024); \
  } } while(0)

// V loads to regs (sequential; flipped-tail map only bites at g=63)
#define LOADV(c) do { int c_ = (c); \
  if (c_ < 8){ \
    int p0v_ = g*GS_ + c_*64 + 2*pair; \
    int p1v_ = p0v_ + 1; \
    int rv0_ = (p0v_ < N_) ? p0v_ : (2*N_ - 1 - p0v_); \
    int rv1_ = (p1v_ < N_) ? p1v_ : (2*N_ - 1 - p1v_); \
    vr0 = *(const us8*)(qkv + (size_t)(b*N_ + rv0_)*1536 + 1024 + h*64 + dvb*8); \
    vr1 = *(const us8*)(qkv + (size_t)(b*N_ + rv1_)*1536 + 1024 + h*64 + dvb*8); \
  } else { \
    vr0 = *(const us8*)(vgb + (size_t)(h*64 + 2*pair)*64 + dvb*8); \
    vr1 = *(const us8*)(vgb + (size_t)(h*64 + 2*pair + 1)*64 + dvb*8); \
  } } while(0)

#define WRITEV(vbuf) do { \
  _Pragma("unroll") \
  for (int j_ = 0; j_ < 8; ++j_){ \
    int r_ = dvb*8 + j_; \
    int byte_ = (r_*128 + pair*4) ^ ((r_ & 7) << 4); \
    *(unsigned*)((char*)(vbuf) + byte_) = (unsigned)vr0[j_] | ((unsigned)vr1[j_] << 16); } \
} while(0)

// ---- attention compute, swapped QK (S^T = mfma(K,Q)), quarter-tile QK to cap
// registers (s_[2][2] = 16 regs), packed-b64 P stores, PV per 32-row half.
#define COMPUTE_CHUNK(KBUF, VBUF, ACC, LAC) do { \
  _Pragma("unroll") \
  for (int mh_ = 0; mh_ < 2; ++mh_){ \
    _Pragma("unroll") \
    for (int nh_ = 0; nh_ < 2; ++nh_){ \
      f32x4 s_[2][2]; \
      _Pragma("unroll") for (int n2_ = 0; n2_ < 2; ++n2_){ \
        _Pragma("unroll") for (int m2_ = 0; m2_ < 2; ++m2_) s_[n2_][m2_] = (f32x4){0.f,0.f,0.f,0.f}; } \
      _Pragma("unroll") for (int ks_ = 0; ks_ < 2; ++ks_){ \
        bf16x8 kf_[2]; \
        _Pragma("unroll") for (int n2_ = 0; n2_ < 2; ++n2_) \
          kf_[n2_] = lds_read8((KBUF), (nh_*2+n2_)*16 + lr, ks_*64 + lg*16); \
        _Pragma("unroll") for (int n2_ = 0; n2_ < 2; ++n2_){ \
          _Pragma("unroll") for (int m2_ = 0; m2_ < 2; ++m2_) \
            s_[n2_][m2_] = __builtin_amdgcn_mfma_f32_16x16x32_bf16(kf_[n2_], qf[mh_*2+m2_][ks_], s_[n2_][m2_], 0, 0, 0); } } \
      _Pragma("unroll") for (int m2_ = 0; m2_ < 2; ++m2_){ \
        float rs_ = 0.f; \
        _Pragma("unroll") for (int n2_ = 0; n2_ < 2; ++n2_){ \
          _Pragma("unroll") for (int j_ = 0; j_ < 4; ++j_){ \
            float p_ = exp2f(s_[n2_][m2_][j_]); s_[n2_][m2_][j_] = p_; rs_ += p_; } } \
        (LAC)[mh_*2+m2_] += rs_; \
        int q_ = m2_*16 + lr; \
        _Pragma("unroll") for (int n2_ = 0; n2_ < 2; ++n2_){ \
          u32x2 pk_; \
          pk_[0] = pk2(s_[n2_][m2_][0], s_[n2_][m2_][1]); \
          pk_[1] = pk2(s_[n2_][m2_][2], s_[n2_][m2_][3]); \
          int byte_ = (q_*128 + (nh_*2+n2_)*32 + lg*8) ^ ((q_ & 7) << 4); \
          *(u32x2*)((char*)Pw + byte_) = pk_; } } \
    } \
    _Pragma("unroll") for (int ks_ = 0; ks_ < 2; ++ks_){ \
      bf16x8 pa_[2], vb_[4]; \
      _Pragma("unroll") for (int m2_ = 0; m2_ < 2; ++m2_) pa_[m2_] = lds_read8(Pw, m2_*16 + lr, ks_*64 + lg*16); \
      _Pragma("unroll") for (int n_ = 0; n_ < 4; ++n_) vb_[n_] = lds_read8((VBUF), n_*16 + lr, ks_*64 + lg*16); \
      _Pragma("unroll") for (int m2_ = 0; m2_ < 2; ++m2_){ \
        _Pragma("unroll") for (int n_ = 0; n_ < 4; ++n_) \
          (ACC)[mh_*2+m2_][n_] = __builtin_amdgcn_mfma_f32_16x16x32_bf16(pa_[m2_], vb_[n_], (ACC)[mh_*2+m2_][n_], 0, 0, 0); } } \
  } \
} while(0)

// ---------------- fused local(512-window) + global(64) attention ----------------
// K: global_load_lds double-buffered (pre-swizzled source), V: reg->LDS dbuf,
// 1 barrier/chunk (R6 schedule). Quarter-tile QK caps loop registers (~135).
// Swapped-QK packed-P (R11), exp2 softmax, deferred lane-local rowsums.
__global__ __launch_bounds__(256, 2) void attn_kernel(
    const u16* __restrict__ qkv,   // [B*N][1536] bf16, permuted order (q pre-scaled)
    const u16* __restrict__ kgb,   // [H][64][64] bf16
    const u16* __restrict__ vgb,   // [H][64][64] bf16
    u16* __restrict__ outp)        // [B*N][512] bf16, permuted order
{
  __shared__ u16 Pl[4][32*64];     // 16KB wave-private P / out staging (4KB each)
  __shared__ u16 Kl[2][64*64];     // 16KB swizzled (via pre-swizzled gload source)
  __shared__ u16 Vl[2][64*64];     // 16KB transposed [dv][t], swizzled

  const int tid = threadIdx.x;
  const int l = tid & 63, w = tid >> 6;
  const int lr = l & 15, lg = l >> 4;
  const int pair = tid & 31, dvb = tid >> 5;

  const int g = blockIdx.x, h = blockIdx.y, b = blockIdx.z;

  // ---- Q fragments straight to registers ----
  bf16x8 qf[4][2];
#pragma unroll
  for (int m = 0; m < 4; ++m){
    int grow = g*GS_ + w*64 + m*16 + lr;
    const u16* qrow = qkv + (size_t)(b*N_ + grow)*1536 + h*64;
#pragma unroll
    for (int ks = 0; ks < 2; ++ks)
      qf[m][ks] = *(const bf16x8*)(qrow + ks*32 + lg*8);
  }

  u16* Pw = Pl[w];                       // wave-private 4KB [32][64] region

  us8 vr0, vr1;
  ISSUEK(0, Kl[0]);
  LOADV(0);
  WRITEV(Vl[0]);                         // one-time exposed vmcnt wait
  __syncthreads();                       // chunk 0 K+V visible
  LOADV(1);
  ISSUEK(1, Kl[1]);

  f32x4 oacc[4][4];
  float lrun[4];
#pragma unroll
  for (int m = 0; m < 4; ++m)
#pragma unroll
    for (int n = 0; n < 4; ++n) oacc[m][n] = (f32x4){0.f,0.f,0.f,0.f};
#pragma unroll
  for (int m = 0; m < 4; ++m) lrun[m] = 0.f;

  for (int c = 0; c < 8; ++c){
    int cur = c & 1;
    COMPUTE_CHUNK(Kl[cur], Vl[cur], oacc, lrun);
    WRITEV(Vl[cur ^ 1]);                 // V(c+1); vmcnt wait covered by compute
    __syncthreads();                     // drains K(c+1) gloads; Vl[cur^1] visible
    if (c < 7){ LOADV(c + 2); ISSUEK(c + 2, Kl[cur]); }
  }
  // after loop: chunk 8 (global attention) resides in Kl[0], Vl[0]

  // ---- finalize local softmax: reduce lane-partial sums, broadcast, divide ----
  float i1[4];
#pragma unroll
  for (int m = 0; m < 4; ++m){
    float s1 = lrun[m];
    s1 += __shfl_xor(s1, 16); s1 += __shfl_xor(s1, 32);
    i1[m] = 1.f / s1;
  }
#pragma unroll
  for (int m = 0; m < 4; ++m)
#pragma unroll
    for (int j = 0; j < 4; ++j){
      float invb = __shfl(i1[m], lg*4 + j);
#pragma unroll
      for (int n = 0; n < 4; ++n) oacc[m][n][j] *= invb;
    }

  // ---- global-attention chunk (Kl[0]/Vl[0]); swapped QK, full-width,
  //      lane-uniform inline normalize, accumulate into oacc ----
  {
    f32x4 s_[4][4];
#pragma unroll
    for (int n_ = 0; n_ < 4; ++n_)
#pragma unroll
      for (int m_ = 0; m_ < 4; ++m_) s_[n_][m_] = (f32x4){0.f,0.f,0.f,0.f};
#pragma unroll
    for (int ks_ = 0; ks_ < 2; ++ks_){
      bf16x8 kf_[4];
#pragma unroll
      for (int n_ = 0; n_ < 4; ++n_) kf_[n_] = lds_read8(Kl[0], n_*16 + lr, ks_*64 + lg*16);
#pragma unroll
      for (int n_ = 0; n_ < 4; ++n_)
#pragma unroll
        for (int m_ = 0; m_ < 4; ++m_)
          s_[n_][m_] = __builtin_amdgcn_mfma_f32_16x16x32_bf16(kf_[n_], qf[m_][ks_], s_[n_][m_], 0, 0, 0);
    }
#pragma unroll
    for (int m_ = 0; m_ < 4; ++m_){
      float rs_ = 0.f;
#pragma unroll
      for (int n_ = 0; n_ < 4; ++n_)
#pragma unroll
        for (int j_ = 0; j_ < 4; ++j_){
          float p_ = exp2f(s_[n_][m_][j_]); s_[n_][m_][j_] = p_; rs_ += p_;
        }
      rs_ += __shfl_xor(rs_, 16); rs_ += __shfl_xor(rs_, 32);
      float iv_ = 1.f / rs_;               // lane-uniform for q = m*16 + lr
#pragma unroll
      for (int n_ = 0; n_ < 4; ++n_)
#pragma unroll
        for (int j_ = 0; j_ < 4; ++j_) s_[n_][m_][j_] *= iv_;
    }
#pragma unroll
    for (int mh_ = 0; mh_ < 2; ++mh_){
#pragma unroll
      for (int m2_ = 0; m2_ < 2; ++m2_){
        int m_ = mh_*2 + m2_;
        int q_ = m2_*16 + lr;
#pragma unroll
        for (int n_ = 0; n_ < 4; ++n_){
          u32x2 pk_;
          pk_[0] = pk2(s_[n_][m_][0], s_[n_][m_][1]);
          pk_[1] = pk2(s_[n_][m_][2], s_[n_][m_][3]);
          int byte_ = (q_*128 + n_*32 + lg*8) ^ ((q_ & 7) << 4);
          *(u32x2*)((char*)Pw + byte_) = pk_;
        }
      }
#pragma unroll
      for (int ks_ = 0; ks_ < 2; ++ks_){
        bf16x8 pa_[2], vb_[4];
#pragma unroll
        for (int m2_ = 0; m2_ < 2; ++m2_) pa_[m2_] = lds_read8(Pw, m2_*16 + lr, ks_*64 + lg*16);
#pragma unroll
        for (int n_ = 0; n_ < 4; ++n_) vb_[n_] = lds_read8(Vl[0], n_*16 + lr, ks_*64 + lg*16);
#pragma unroll
        for (int m2_ = 0; m2_ < 2; ++m2_)
#pragma unroll
          for (int n_ = 0; n_ < 4; ++n_)
            oacc[mh_*2+m2_][n_] = __builtin_amdgcn_mfma_f32_16x16x32_bf16(pa_[m2_], vb_[n_], oacc[mh_*2+m2_][n_], 0, 0, 0);
      }
    }
  }

  // ---- epilogue: stage half to LDS, coalesced sequential write, twice ----
#pragma unroll
  for (int mh = 0; mh < 2; ++mh){
#pragma unroll
    for (int m2 = 0; m2 < 2; ++m2)
#pragma unroll
      for (int n = 0; n < 4; ++n)
#pragma unroll
        for (int j = 0; j < 4; ++j){
          int row = m2*16 + lg*4 + j, col = n*16 + lr;
          int byte = (row*128 + col*2) ^ ((row & 7) << 4);
          *(u16*)((char*)Pw + byte) = f2bh(oacc[mh*2+m2][n][j]);
        }
    __builtin_amdgcn_s_waitcnt(0);  // drain before re-reading wave-private Pw
#pragma unroll
    for (int i4 = 0; i4 < 4; ++i4){
      int o = i4*1024 + l*16;
      int row = o >> 7, c8 = (o & 127) >> 4;
      int addr = o ^ ((row & 7) << 4);
      u32x4 d = *(const u32x4*)((const char*)Pw + addr);
      int orow = g*GS_ + w*64 + mh*32 + row;
      *(u32x4*)(outp + (size_t)(b*N_ + orow)*512 + h*64 + c8*8) = d;
    }
  }
}

extern "C" void kernel_launch(void* const* d_in, const int* in_sizes, int n_in,
                              void* d_out, int out_size, void* d_ws, size_t ws_size,
                              hipStream_t stream)
{
  const float* x  = (const float*)d_in[0];
  const int*  idx = (const int*)d_in[1];
  const float* kg = (const float*)d_in[2];
  const float* vg = (const float*)d_in[3];
  const float* Wq = (const float*)d_in[4];
  const float* Wk = (const float*)d_in[5];
  const float* Wv = (const float*)d_in[6];
  const float* Wp = (const float*)d_in[7];
  float* out = (float*)d_out;

  char* ws = (char*)d_ws;
  u16* Xb   = (u16*)ws;                                   // reused as attn_o
  u16* qkv  = (u16*)(ws + 33554432);
  u16* Wqt  = (u16*)(ws + 134217728);
  u16* Wkt  = (u16*)(ws + 134217728 + 524288);
  u16* Wvt  = (u16*)(ws + 134217728 + 2*524288);
  u16* Wpt  = (u16*)(ws + 134217728 + 3*524288);
  u16* kgb  = (u16*)(ws + 134217728 + 4*524288);
  u16* vgb  = (u16*)(ws + 134217728 + 4*524288 + 65536);
  u16* attn_o = Xb;  // safe: gemm_qkv (reads Xb) completes before attn writes

  cvt_f32_bf16<<<16384, 256, 0, stream>>>((const float4*)x, (us4*)Xb, 16777216/4);
  cvt_f32_bf16<<<32, 256, 0, stream>>>((const float4*)kg, (us4*)kgb, 32768/4);
  cvt_f32_bf16<<<32, 256, 0, stream>>>((const float4*)vg, (us4*)vgb, 32768/4);
  cvt_w_t<<<dim3(32,32,4), 256, 0, stream>>>(Wq, Wk, Wv, Wp, Wqt, Wkt, Wvt, Wpt);
  // qkv GEMM gathers A-rows via idx -> qkv in PERMUTED order (q pre-scaled by 0.125*log2e)
  gemm_bf16k<u16, true, true, false><<<dim3(256,12), 256, 0, stream>>>(Xb, Wqt, Wkt, Wvt, idx, qkv, 1536);
  // attention: sequential accesses, K via gload_lds (pre-swizzled source), 1 barrier/chunk
  attn_kernel<<<dim3(64,8,2), 256, 0, stream>>>(qkv, kgb, vgb, attn_o);
  // proj GEMM scatters C-rows via idx -> out back in token order
  gemm_bf16k<float, false, false, true><<<dim3(256,4), 256, 0, stream>>>(attn_o, Wpt, Wpt, Wpt, idx, out, 512);
}

// Round 13
// 205.301 us; speedup vs baseline: 1.1572x; 1.1572x over previous
//
#include <hip/hip_runtime.h>
#include <hip/hip_bf16.h>

#define B_   2
#define N_   16384
#define H_   8
#define GS_  256
#define NG_  64

typedef unsigned short u16;
typedef __attribute__((ext_vector_type(8))) short bf16x8;
typedef __attribute__((ext_vector_type(4))) float f32x4;
typedef __attribute__((ext_vector_type(8))) unsigned short us8;
typedef __attribute__((ext_vector_type(4))) unsigned short us4;
typedef __attribute__((ext_vector_type(4))) unsigned int u32x4;
typedef __attribute__((ext_vector_type(2))) unsigned int u32x2;

__device__ __forceinline__ u16 f2b(float f){
  union { float f; unsigned u; } v; v.f = f;
  unsigned r = v.u + 0x7fffu + ((v.u >> 16) & 1u);
  return (u16)(r >> 16);
}

__device__ __forceinline__ u16 f2bh(float f){
  __hip_bfloat16 h = __float2bfloat16(f);
  u16 u; __builtin_memcpy(&u, &h, 2);
  return u;
}

// pack two floats into one u32 of 2 bf16 (lo = a, hi = b) — HW packed convert
__device__ __forceinline__ unsigned pk2(float a, float b){
  unsigned r;
  asm("v_cvt_pk_bf16_f32 %0, %1, %2" : "=v"(r) : "v"(a), "v"(b));
  return r;
}

__device__ __forceinline__ void gload16(const void* g, const void* lds){
  __builtin_amdgcn_global_load_lds(
      (const __attribute__((address_space(1))) void*)g,
      (__attribute__((address_space(3))) void*)lds, 16, 0, 0);
}

// swizzled 16B fragment read from a [rows][64] bf16 tile (row stride 128B)
__device__ __forceinline__ bf16x8 lds_read8(const u16* base, int row, int coloff){
  int byte = (row*128 + coloff) ^ ((row & 7) << 4);
  return *(const bf16x8*)((const char*)base + byte);
}

__device__ __forceinline__ void stout(float* p, float v){ *p = v; }
__device__ __forceinline__ void stout(u16* p, float v){ *p = f2b(v); }

// ---------------- fp32 -> bf16 vector convert ----------------
__global__ void cvt_f32_bf16(const float4* __restrict__ in, us4* __restrict__ out, int n4){
  int i = blockIdx.x * 256 + threadIdx.x;
  if (i < n4){
    float4 v = in[i];
    us4 o;
    o[0] = f2b(v.x); o[1] = f2b(v.y); o[2] = f2b(v.z); o[3] = f2b(v.w);
    out[i] = o;
  }
}

// ---------------- weight convert + transpose: T[n][k] = bf16(W[k][n]) ----------------
__global__ void cvt_w_t(const float* __restrict__ W0, const float* __restrict__ W1,
                        const float* __restrict__ W2, const float* __restrict__ W3,
                        u16* __restrict__ T0, u16* __restrict__ T1,
                        u16* __restrict__ T2, u16* __restrict__ T3)
{
  int z = blockIdx.z;
  const float* W = (z==0)?W0:((z==1)?W1:((z==2)?W2:W3));
  u16* T = (z==0)?T0:((z==1)?T1:((z==2)?T2:T3));
  __shared__ float tile[16][17];
  int tx = threadIdx.x & 15, ty = threadIdx.x >> 4;
  int k0 = blockIdx.x*16, n0 = blockIdx.y*16;
  tile[ty][tx] = W[(k0+ty)*512 + n0 + tx];
  __syncthreads();
  T[(n0+ty)*512 + k0 + tx] = f2b(tile[tx][ty]);
}

// ---------------- bf16 GEMM: C = A @ Wt^T (R8-proven form) ----------------
// GATHA: A-rows gathered through perm (qkv GEMM -> output in permuted order).
// SCATC: C-rows scattered through perm (proj GEMM -> output in token order).
// q cols pre-scaled by 0.125*log2(e) (exp2 softmax downstream).
template<typename OUT_T, bool MULTI, bool GATHA, bool SCATC>
__global__ __launch_bounds__(256, 2) void gemm_bf16k(
    const u16* __restrict__ A,
    const u16* __restrict__ Wt0, const u16* __restrict__ Wt1, const u16* __restrict__ Wt2,
    const int* __restrict__ perm,   // [B][N] permutation
    OUT_T* __restrict__ C, int ldc)
{
  __shared__ u16 Al[128*64];
  __shared__ u16 Bl[128*64];
  const int tid = threadIdx.x;
  const int l = tid & 63, w = tid >> 6;
  const int lr = l & 15, lg = l >> 4;
  const int bm = blockIdx.x, bn = blockIdx.y;
  const int wr = (w >> 1) * 64, wc = (w & 1) * 64;

  const u16* Wt; int ocolb; float qsc;
  if (MULTI){
    int wsel = bn >> 2;
    Wt = (wsel == 0) ? Wt0 : ((wsel == 1) ? Wt1 : Wt2);
    ocolb = (bn & 3) * 128;
    qsc = (wsel == 0) ? 0.18033688f : 1.0f;   // 0.125 * log2(e)
  } else { Wt = Wt0; ocolb = bn * 128; qsc = 1.0f; }

  // per-thread A-row indices (4 rows), gather-translated once
  int arows[4];
#pragma unroll
  for (int i = 0; i < 4; ++i){
    int r = bm*128 + i*32 + (tid >> 3);
    arows[i] = GATHA ? ((r & ~(N_-1)) + perm[r]) : r;
  }

  f32x4 acc[4][4];
#pragma unroll
  for (int m = 0; m < 4; ++m)
#pragma unroll
    for (int n = 0; n < 4; ++n) acc[m][n] = (f32x4){0.f,0.f,0.f,0.f};

  const int c8 = tid & 7;
  for (int kk = 0; kk < 512; kk += 64){
#pragma unroll
    for (int i = 0; i < 4; ++i){
      int o = i*4096 + tid*16;
      int brow = o >> 7;
      gload16(A  + (size_t)arows[i]*512 + kk + c8*8, (const char*)Al + i*4096 + w*1024);
      gload16(Wt + (size_t)(ocolb + brow)*512 + kk + c8*8, (const char*)Bl + i*4096 + w*1024);
    }
    __syncthreads();
#pragma unroll
    for (int ks = 0; ks < 2; ++ks){
      bf16x8 af[4], bfv[4];
#pragma unroll
      for (int m = 0; m < 4; ++m) af[m]  = *(const bf16x8*)&Al[(wr + m*16 + lr)*64 + ks*32 + lg*8];
#pragma unroll
      for (int n = 0; n < 4; ++n) bfv[n] = *(const bf16x8*)&Bl[(wc + n*16 + lr)*64 + ks*32 + lg*8];
#pragma unroll
      for (int m = 0; m < 4; ++m)
#pragma unroll
        for (int n = 0; n < 4; ++n)
          acc[m][n] = __builtin_amdgcn_mfma_f32_16x16x32_bf16(af[m], bfv[n], acc[m][n], 0, 0, 0);
    }
    __syncthreads();
  }
#pragma unroll
  for (int m = 0; m < 4; ++m)
#pragma unroll
    for (int n = 0; n < 4; ++n)
#pragma unroll
      for (int j = 0; j < 4; ++j){
        int row = bm*128 + wr + m*16 + lg*4 + j;
        int col = bn*128 + wc + n*16 + lr;
        size_t orow = SCATC ? (size_t)((row & ~(N_-1)) + perm[row]) : (size_t)row;
        stout(&C[orow*ldc + col], acc[m][n][j] * qsc);
      }
}

// ---- attention compute, SWAPPED QK (S^T = mfma(K,Q)) + packed-b64 P stores ----
// s_[n_token][m_q]: lane holds S[t=n*16+lg*4+j][q=m*16+lr]. Rowsum is lane-local.
// P store: per (m,n) one ds_write_b64 of 4 consecutive tokens (v_cvt_pk HW pack).
#define COMPUTE_CHUNK(KBUF, VBUF, ACC, LAC) do { \
  f32x4 s_[4][4]; \
  _Pragma("unroll") \
  for (int n_ = 0; n_ < 4; ++n_){ _Pragma("unroll") for (int m_ = 0; m_ < 4; ++m_) s_[n_][m_] = (f32x4){0.f,0.f,0.f,0.f}; } \
  _Pragma("unroll") \
  for (int ks_ = 0; ks_ < 2; ++ks_){ \
    bf16x8 kf_[4]; \
    _Pragma("unroll") for (int n_ = 0; n_ < 4; ++n_) kf_[n_] = lds_read8((KBUF), n_*16 + lr, ks_*64 + lg*16); \
    _Pragma("unroll") for (int n_ = 0; n_ < 4; ++n_){ \
      _Pragma("unroll") for (int m_ = 0; m_ < 4; ++m_) \
        s_[n_][m_] = __builtin_amdgcn_mfma_f32_16x16x32_bf16(kf_[n_], qf[m_][ks_], s_[n_][m_], 0, 0, 0); } } \
  _Pragma("unroll") \
  for (int m_ = 0; m_ < 4; ++m_){ \
    float rs_ = 0.f; \
    _Pragma("unroll") for (int n_ = 0; n_ < 4; ++n_){ \
      _Pragma("unroll") for (int j_ = 0; j_ < 4; ++j_){ \
        float p_ = exp2f(s_[n_][m_][j_]); s_[n_][m_][j_] = p_; rs_ += p_; } } \
    (LAC)[m_] += rs_; } \
  _Pragma("unroll") \
  for (int mh_ = 0; mh_ < 2; ++mh_){ \
    _Pragma("unroll") for (int m2_ = 0; m2_ < 2; ++m2_){ \
      int m_ = mh_*2 + m2_; \
      int q_ = m2_*16 + lr; \
      _Pragma("unroll") for (int n_ = 0; n_ < 4; ++n_){ \
        u32x2 pk_; \
        pk_[0] = pk2(s_[n_][m_][0], s_[n_][m_][1]); \
        pk_[1] = pk2(s_[n_][m_][2], s_[n_][m_][3]); \
        int byte_ = (q_*128 + n_*32 + lg*8) ^ ((q_ & 7) << 4); \
        *(u32x2*)((char*)Pw + byte_) = pk_; } } \
    _Pragma("unroll") for (int ks_ = 0; ks_ < 2; ++ks_){ \
      bf16x8 pa_[2], vb_[4]; \
      _Pragma("unroll") for (int m2_ = 0; m2_ < 2; ++m2_) pa_[m2_] = lds_read8(Pw, m2_*16 + lr, ks_*64 + lg*16); \
      _Pragma("unroll") for (int n_ = 0; n_ < 4; ++n_) vb_[n_] = lds_read8((VBUF), n_*16 + lr, ks_*64 + lg*16); \
      _Pragma("unroll") for (int m2_ = 0; m2_ < 2; ++m2_){ \
        _Pragma("unroll") for (int n_ = 0; n_ < 4; ++n_) \
          (ACC)[mh_*2+m2_][n_] = __builtin_amdgcn_mfma_f32_16x16x32_bf16(pa_[m2_], vb_[n_], (ACC)[mh_*2+m2_][n_], 0, 0, 0); } } \
  } \
} while(0)

// sequential K/V loads into regs (flipped-tail map only bites at g=63)
#define LOADKV(c) do { int c_ = (c); \
  if (c_ < 8){ \
    int p0k_ = g*GS_ + c_*64 + krow_; \
    int p1k_ = p0k_ + 32; \
    int rk0_ = (p0k_ < N_) ? p0k_ : (2*N_ - 1 - p0k_); \
    int rk1_ = (p1k_ < N_) ? p1k_ : (2*N_ - 1 - p1k_); \
    kr0 = *(const us8*)(qkv + (size_t)(b*N_ + rk0_)*1536 + 512 + h*64 + kc8_*8); \
    kr1 = *(const us8*)(qkv + (size_t)(b*N_ + rk1_)*1536 + 512 + h*64 + kc8_*8); \
    int p0v_ = g*GS_ + c_*64 + 2*pair; \
    int p1v_ = p0v_ + 1; \
    int rv0_ = (p0v_ < N_) ? p0v_ : (2*N_ - 1 - p0v_); \
    int rv1_ = (p1v_ < N_) ? p1v_ : (2*N_ - 1 - p1v_); \
    vr0 = *(const us8*)(qkv + (size_t)(b*N_ + rv0_)*1536 + 1024 + h*64 + dvb*8); \
    vr1 = *(const us8*)(qkv + (size_t)(b*N_ + rv1_)*1536 + 1024 + h*64 + dvb*8); \
  } else { \
    kr0 = *(const us8*)(kgb + (size_t)(h*64 + krow_)*64 + kc8_*8); \
    kr1 = *(const us8*)(kgb + (size_t)(h*64 + 32 + krow_)*64 + kc8_*8); \
    vr0 = *(const us8*)(vgb + (size_t)(h*64 + 2*pair)*64 + dvb*8); \
    vr1 = *(const us8*)(vgb + (size_t)(h*64 + 2*pair + 1)*64 + dvb*8); \
  } } while(0)

#define WRITEKV() do { \
  { int r0_ = krow_, r1_ = 32 + krow_; \
    *(us8*)((char*)Kb + ((r0_*128 + kc8_*16) ^ ((r0_ & 7) << 4))) = kr0; \
    *(us8*)((char*)Kb + ((r1_*128 + kc8_*16) ^ ((r1_ & 7) << 4))) = kr1; } \
  _Pragma("unroll") \
  for (int j_ = 0; j_ < 8; ++j_){ \
    int r_ = dvb*8 + j_; \
    int byte_ = (r_*128 + pair*4) ^ ((r_ & 7) << 4); \
    *(unsigned*)((char*)Vb + byte_) = (unsigned)vr0[j_] | ((unsigned)vr1[j_] << 16); } \
} while(0)

// ---------------- fused local(512-window) + global(64) attention ----------------
// R11 structure exactly (32KB LDS, single K/V buffer, depth-1 staging,
// 2 barriers/chunk, grid (g,h,b), FETCH=93MB proven) + HW v_cvt_pk_bf16_f32
// for the P pack (cuts ~300 VALU ops/chunk from the serial chain).
__global__ __launch_bounds__(256, 2) void attn_kernel(
    const u16* __restrict__ qkv,   // [B*N][1536] bf16, permuted order (q pre-scaled)
    const u16* __restrict__ kgb,   // [H][64][64] bf16
    const u16* __restrict__ vgb,   // [H][64][64] bf16
    u16* __restrict__ outp)        // [B*N][512] bf16, permuted order
{
  __shared__ u16 Pl[4][32*64];     // 16KB wave-private P / out staging (4KB each)
  __shared__ u16 Kb[64*64];        // 8KB swizzled
  __shared__ u16 Vb[64*64];        // 8KB transposed [dv][t], swizzled

  const int tid = threadIdx.x;
  const int l = tid & 63, w = tid >> 6;
  const int lr = l & 15, lg = l >> 4;
  const int pair = tid & 31, dvb = tid >> 5;
  const int krow_ = tid >> 3, kc8_ = tid & 7;

  const int g = blockIdx.x, h = blockIdx.y, b = blockIdx.z;

  // ---- Q fragments straight to registers ----
  bf16x8 qf[4][2];
#pragma unroll
  for (int m = 0; m < 4; ++m){
    int grow = g*GS_ + w*64 + m*16 + lr;
    const u16* qrow = qkv + (size_t)(b*N_ + grow)*1536 + h*64;
#pragma unroll
    for (int ks = 0; ks < 2; ++ks)
      qf[m][ks] = *(const bf16x8*)(qrow + ks*32 + lg*8);
  }

  u16* Pw = Pl[w];                       // wave-private 4KB [32][64] region

  us8 kr0, kr1, vr0, vr1;
  LOADKV(0);
  WRITEKV();                             // one-time exposed vmcnt wait
  __syncthreads();                       // chunk 0 visible

  f32x4 oacc[4][4];
  float lrun[4];
#pragma unroll
  for (int m = 0; m < 4; ++m)
#pragma unroll
    for (int n = 0; n < 4; ++n) oacc[m][n] = (f32x4){0.f,0.f,0.f,0.f};
#pragma unroll
  for (int m = 0; m < 4; ++m) lrun[m] = 0.f;

  for (int c = 0; c < 8; ++c){
    LOADKV(c + 1);                       // c==7 loads global K/V; in flight across compute
    COMPUTE_CHUNK(Kb, Vb, oacc, lrun);
    __syncthreads();                     // all waves done reading Kb/Vb
    WRITEKV();                           // vmcnt wait covered by the compute above
    __syncthreads();                     // next chunk visible
  }

  // ---- finalize local softmax: reduce lane-partial sums, broadcast, divide ----
  float i1[4];
#pragma unroll
  for (int m = 0; m < 4; ++m){
    float s1 = lrun[m];
    s1 += __shfl_xor(s1, 16); s1 += __shfl_xor(s1, 32);
    i1[m] = 1.f / s1;
  }
#pragma unroll
  for (int m = 0; m < 4; ++m)
#pragma unroll
    for (int j = 0; j < 4; ++j){
      float invb = __shfl(i1[m], lg*4 + j);
#pragma unroll
      for (int n = 0; n < 4; ++n) oacc[m][n][j] *= invb;
    }

  // ---- global-attention chunk (chunk 8, resident in Kb/Vb); swapped QK,
  //      lane-uniform inline normalize, accumulate into oacc ----
  {
    f32x4 s_[4][4];
#pragma unroll
    for (int n_ = 0; n_ < 4; ++n_)
#pragma unroll
      for (int m_ = 0; m_ < 4; ++m_) s_[n_][m_] = (f32x4){0.f,0.f,0.f,0.f};
#pragma unroll
    for (int ks_ = 0; ks_ < 2; ++ks_){
      bf16x8 kf_[4];
#pragma unroll
      for (int n_ = 0; n_ < 4; ++n_) kf_[n_] = lds_read8(Kb, n_*16 + lr, ks_*64 + lg*16);
#pragma unroll
      for (int n_ = 0; n_ < 4; ++n_)
#pragma unroll
        for (int m_ = 0; m_ < 4; ++m_)
          s_[n_][m_] = __builtin_amdgcn_mfma_f32_16x16x32_bf16(kf_[n_], qf[m_][ks_], s_[n_][m_], 0, 0, 0);
    }
#pragma unroll
    for (int m_ = 0; m_ < 4; ++m_){
      float rs_ = 0.f;
#pragma unroll
      for (int n_ = 0; n_ < 4; ++n_)
#pragma unroll
        for (int j_ = 0; j_ < 4; ++j_){
          float p_ = exp2f(s_[n_][m_][j_]); s_[n_][m_][j_] = p_; rs_ += p_;
        }
      rs_ += __shfl_xor(rs_, 16); rs_ += __shfl_xor(rs_, 32);
      float iv_ = 1.f / rs_;               // lane-uniform for q = m*16 + lr
#pragma unroll
      for (int n_ = 0; n_ < 4; ++n_)
#pragma unroll
        for (int j_ = 0; j_ < 4; ++j_) s_[n_][m_][j_] *= iv_;
    }
#pragma unroll
    for (int mh_ = 0; mh_ < 2; ++mh_){
#pragma unroll
      for (int m2_ = 0; m2_ < 2; ++m2_){
        int m_ = mh_*2 + m2_;
        int q_ = m2_*16 + lr;
#pragma unroll
        for (int n_ = 0; n_ < 4; ++n_){
          u32x2 pk_;
          pk_[0] = pk2(s_[n_][m_][0], s_[n_][m_][1]);
          pk_[1] = pk2(s_[n_][m_][2], s_[n_][m_][3]);
          int byte_ = (q_*128 + n_*32 + lg*8) ^ ((q_ & 7) << 4);
          *(u32x2*)((char*)Pw + byte_) = pk_;
        }
      }
#pragma unroll
      for (int ks_ = 0; ks_ < 2; ++ks_){
        bf16x8 pa_[2], vb_[4];
#pragma unroll
        for (int m2_ = 0; m2_ < 2; ++m2_) pa_[m2_] = lds_read8(Pw, m2_*16 + lr, ks_*64 + lg*16);
#pragma unroll
        for (int n_ = 0; n_ < 4; ++n_) vb_[n_] = lds_read8(Vb, n_*16 + lr, ks_*64 + lg*16);
#pragma unroll
        for (int m2_ = 0; m2_ < 2; ++m2_)
#pragma unroll
          for (int n_ = 0; n_ < 4; ++n_)
            oacc[mh_*2+m2_][n_] = __builtin_amdgcn_mfma_f32_16x16x32_bf16(pa_[m2_], vb_[n_], oacc[mh_*2+m2_][n_], 0, 0, 0);
      }
    }
  }

  // ---- epilogue: stage half to LDS, coalesced sequential write, twice ----
#pragma unroll
  for (int mh = 0; mh < 2; ++mh){
#pragma unroll
    for (int m2 = 0; m2 < 2; ++m2)
#pragma unroll
      for (int n = 0; n < 4; ++n)
#pragma unroll
        for (int j = 0; j < 4; ++j){
          int row = m2*16 + lg*4 + j, col = n*16 + lr;
          int byte = (row*128 + col*2) ^ ((row & 7) << 4);
          *(u16*)((char*)Pw + byte) = f2bh(oacc[mh*2+m2][n][j]);
        }
    __builtin_amdgcn_s_waitcnt(0);  // drain before re-reading wave-private Pw
#pragma unroll
    for (int i4 = 0; i4 < 4; ++i4){
      int o = i4*1024 + l*16;
      int row = o >> 7, c8 = (o & 127) >> 4;
      int addr = o ^ ((row & 7) << 4);
      u32x4 d = *(const u32x4*)((const char*)Pw + addr);
      int orow = g*GS_ + w*64 + mh*32 + row;
      *(u32x4*)(outp + (size_t)(b*N_ + orow)*512 + h*64 + c8*8) = d;
    }
  }
}

extern "C" void kernel_launch(void* const* d_in, const int* in_sizes, int n_in,
                              void* d_out, int out_size, void* d_ws, size_t ws_size,
                              hipStream_t stream)
{
  const float* x  = (const float*)d_in[0];
  const int*  idx = (const int*)d_in[1];
  const float* kg = (const float*)d_in[2];
  const float* vg = (const float*)d_in[3];
  const float* Wq = (const float*)d_in[4];
  const float* Wk = (const float*)d_in[5];
  const float* Wv = (const float*)d_in[6];
  const float* Wp = (const float*)d_in[7];
  float* out = (float*)d_out;

  char* ws = (char*)d_ws;
  u16* Xb   = (u16*)ws;                                   // reused as attn_o
  u16* qkv  = (u16*)(ws + 33554432);
  u16* Wqt  = (u16*)(ws + 134217728);
  u16* Wkt  = (u16*)(ws + 134217728 + 524288);
  u16* Wvt  = (u16*)(ws + 134217728 + 2*524288);
  u16* Wpt  = (u16*)(ws + 134217728 + 3*524288);
  u16* kgb  = (u16*)(ws + 134217728 + 4*524288);
  u16* vgb  = (u16*)(ws + 134217728 + 4*524288 + 65536);
  u16* attn_o = Xb;  // safe: gemm_qkv (reads Xb) completes before attn writes

  cvt_f32_bf16<<<16384, 256, 0, stream>>>((const float4*)x, (us4*)Xb, 16777216/4);
  cvt_f32_bf16<<<32, 256, 0, stream>>>((const float4*)kg, (us4*)kgb, 32768/4);
  cvt_f32_bf16<<<32, 256, 0, stream>>>((const float4*)vg, (us4*)vgb, 32768/4);
  cvt_w_t<<<dim3(32,32,4), 256, 0, stream>>>(Wq, Wk, Wv, Wp, Wqt, Wkt, Wvt, Wpt);
  // qkv GEMM gathers A-rows via idx -> qkv in PERMUTED order (q pre-scaled by 0.125*log2e)
  gemm_bf16k<u16, true, true, false><<<dim3(256,12), 256, 0, stream>>>(Xb, Wqt, Wkt, Wvt, idx, qkv, 1536);
  // attention: fully sequential accesses, swapped-QK packed-P (HW cvt_pk)
  attn_kernel<<<dim3(64,8,2), 256, 0, stream>>>(qkv, kgb, vgb, attn_o);
  // proj GEMM scatters C-rows via idx -> out back in token order
  gemm_bf16k<float, false, false, true><<<dim3(256,4), 256, 0, stream>>>(attn_o, Wpt, Wpt, Wpt, idx, out, 512);
}